// Round 10
// baseline (313.159 us; speedup 1.0000x reference)
//
#include <hip/hip_runtime.h>
#include <stdint.h>

// Problem constants
#define BB 2
#define SS 2048
#define DD 1024
#define HH 16
#define DKK 64

typedef unsigned short u16;
typedef short short8 __attribute__((ext_vector_type(8)));
typedef float f32x4 __attribute__((ext_vector_type(4)));
typedef u16 u16x4 __attribute__((ext_vector_type(4)));

// fold (1/sqrt(dk)) * log2(e) into q so scores feed exp2 directly
#define QSCALE 0.18033688011112042f

__device__ __forceinline__ u16 f2bf(float x){
  union { float f; uint32_t u; } v; v.f = x;
  uint32_t r = v.u + 0x7FFFu + ((v.u >> 16) & 1u);
  return (u16)(r >> 16);
}

struct ProjArgs {
  const void* A;      // fp32 [4096][1024] (AF32) or bf16 [4096][1024]
  const float* W;     // fp32 [1024][1024], row n = W[n][:]  (B = W^T)
  const float* bias;  // fp32 [1024]
  void* out;
  int mode;           // 0: q bf16 [bh][s][64]; 1: K frag-major; 2: V frag-major; 3: fp32
  float oscale;       // applied after bias add (QSCALE for q, else 1)
};

// ---------------- projection GEMM, 128x128 tile, 8 waves (2x4), BK=32 --------
template<bool AF32>
__global__ __launch_bounds__(512)
void proj_kernel(ProjArgs a0, ProjArgs a1, ProjArgs a2)
{
  ProjArgs pa = (blockIdx.z == 0) ? a0 : (blockIdx.z == 1 ? a1 : a2);
  const int K = 1024;
  __shared__ __align__(16) u16 As[128*32];
  __shared__ __align__(16) u16 Bs[128*32];

  int tid = threadIdx.x;
  int wid = tid >> 6, lane = tid & 63;
  int lg = lane >> 4, lr = lane & 15;
  int tm = blockIdx.x * 128, tn = blockIdx.y * 128;
  int wr = (wid >> 2) * 64, wc = (wid & 3) * 32;

  const float* Af = (const float*)pa.A;
  const u16*   Ab = (const u16*)pa.A;
  const float* Wf = pa.W;

  f32x4 acc[4][2];
  #pragma unroll
  for (int m=0;m<4;m++)
    #pragma unroll
    for (int n=0;n<2;n++){ f32x4 z = {0.f,0.f,0.f,0.f}; acc[m][n] = z; }

  float4 raf[2], rbf[2];
  short8 rab;

  int s0 = tid,        r0 = s0 >> 3, c0 = (s0 & 7) * 4;
  int s1 = 512 + tid,  r1 = s1 >> 3, c1 = (s1 & 7) * 4;
  int rb_ = tid >> 2,  cb_ = (tid & 3) * 8;

  #define LOAD_TILE(kt)                                                        \
    do {                                                                       \
      if (AF32){                                                               \
        raf[0] = *(const float4*)(Af + (size_t)(tm + r0)*K + (kt) + c0);       \
        raf[1] = *(const float4*)(Af + (size_t)(tm + r1)*K + (kt) + c1);       \
      } else {                                                                 \
        rab = *(const short8*)(Ab + (size_t)(tm + rb_)*K + (kt) + cb_);        \
      }                                                                        \
      rbf[0] = *(const float4*)(Wf + (size_t)(tn + r0)*K + (kt) + c0);         \
      rbf[1] = *(const float4*)(Wf + (size_t)(tn + r1)*K + (kt) + c1);         \
    } while (0)

  LOAD_TILE(0);

  for (int kt = 0; kt < K; kt += 32){
    __syncthreads();
    if (AF32){
      u16x4 h0, h1;
      h0[0]=f2bf(raf[0].x); h0[1]=f2bf(raf[0].y); h0[2]=f2bf(raf[0].z); h0[3]=f2bf(raf[0].w);
      h1[0]=f2bf(raf[1].x); h1[1]=f2bf(raf[1].y); h1[2]=f2bf(raf[1].z); h1[3]=f2bf(raf[1].w);
      *(u16x4*)(As + r0*32 + c0) = h0;
      *(u16x4*)(As + r1*32 + c1) = h1;
    } else {
      *(short8*)(As + rb_*32 + cb_) = rab;
    }
    {
      u16x4 h0, h1;
      h0[0]=f2bf(rbf[0].x); h0[1]=f2bf(rbf[0].y); h0[2]=f2bf(rbf[0].z); h0[3]=f2bf(rbf[0].w);
      h1[0]=f2bf(rbf[1].x); h1[1]=f2bf(rbf[1].y); h1[2]=f2bf(rbf[1].z); h1[3]=f2bf(rbf[1].w);
      *(u16x4*)(Bs + r0*32 + c0) = h0;
      *(u16x4*)(Bs + r1*32 + c1) = h1;
    }
    __syncthreads();
    if (kt + 32 < K) LOAD_TILE(kt + 32);

    short8 af[4], bf[2];
    #pragma unroll
    for (int m=0;m<4;m++) af[m] = *(const short8*)(As + (wr + m*16 + lr)*32 + lg*8);
    #pragma unroll
    for (int n=0;n<2;n++) bf[n] = *(const short8*)(Bs + (wc + n*16 + lr)*32 + lg*8);
    #pragma unroll
    for (int m=0;m<4;m++)
      #pragma unroll
      for (int n=0;n<2;n++)
        acc[m][n] = __builtin_amdgcn_mfma_f32_16x16x32_bf16(af[m], bf[n], acc[m][n], 0,0,0);
  }
  #undef LOAD_TILE

  #pragma unroll
  for (int m=0;m<4;m++){
    #pragma unroll
    for (int n=0;n<2;n++){
      #pragma unroll
      for (int r=0;r<4;r++){
        int gm = tm + wr + m*16 + lg*4 + r;
        int gn = tn + wc + n*16 + lr;
        float v = (acc[m][n][r] + pa.bias[gn]) * pa.oscale;
        if (pa.mode == 3){
          ((float*)pa.out)[(size_t)gm*DD + gn] = v;
        } else {
          int b_ = gm >> 11, s_ = gm & 2047;
          int h_ = gn >> 6,  d_ = gn & 63;
          int bh = b_*HH + h_;
          u16 hv = f2bf(v);
          if (pa.mode == 0){
            ((u16*)pa.out)[((size_t)bh*SS + s_)*DKK + d_] = hv;
          } else if (pa.mode == 1){
            // K frag-major
            int c   = s_ >> 5;
            int lr2 = s_ & 15;
            int tl  = (s_ >> 4) & 1;
            int sub = tl*2 + (d_ >> 5);
            int lg2 = (d_ >> 3) & 3;
            int e   = d_ & 7;
            ((u16*)pa.out)[(((size_t)bh*64 + c)*4 + sub)*512 + (lg2*16 + lr2)*8 + e] = hv;
          } else {
            // V frag-major
            int c   = s_ >> 5;
            int lg2 = (s_ >> 3) & 3;
            int e   = s_ & 7;
            int dt  = d_ >> 4;
            int lr2 = d_ & 15;
            ((u16*)pa.out)[(((size_t)bh*64 + c)*4 + dt)*512 + (lg2*16 + lr2)*8 + e] = hv;
          }
        }
      }
    }
  }
}

// ---------------- fused attention (round-9 structure, 128-thr blocks) --------
// Block = 128 thr = 1 wave-pair owning 32 q-rows. Same per-wave work and L2
// traffic as the 256-thr version, but LDS/block drops 27->13.5 KB so ~11
// blocks/CU are resident (22 waves/CU vs 16) - more TLP for the
// latency-bound regime, and the pair-combine barrier spans only 2 waves.
// Pass 1: waves split K-chunks by parity: swapped QK^T -> exp2 -> partial
//   rowsum + partial PV; one barrier to combine. Pass 2: waves split by
//   row-half: recompute QK^T (bit-identical MFMA order), scale by inv_l,
//   plain f32x4 stores. XCD swizzle: each XCD owns 4 bh slices (2MB K+V <= L2).
__global__ __launch_bounds__(128)
void attn_fused_kernel(const u16* __restrict__ qb, const u16* __restrict__ kf,
                       const u16* __restrict__ vf, float* __restrict__ attn_out,
                       u16* __restrict__ ctx)
{
  __shared__ __align__(16) u16 ptile[2][1280];    // per-wave [32][40] u16
  __shared__ f32x4 accbuf[64][8];                 // 8 KB pair-combine
  __shared__ float rsbuf[2][32];

  int tid = threadIdx.x;
  int w = tid >> 6, lane = tid & 63;
  int lg = lane >> 4, lr = lane & 15;
  int par = w;                          // wave parity within the pair
  int L  = blockIdx.x;                  // 0..2047
  int bh = (L & 7)*4 + ((L >> 3) & 3);  // XCD (L%8) owns bh in [4x, 4x+3]
  int qg = L >> 5;                      // 0..63, 32 q-rows

  const u16* qp = qb + ((size_t)bh*SS + qg*32)*DKK;
  const u16* kp = kf + (size_t)bh*131072;
  const u16* vp = vf + (size_t)bh*131072;
  u16* myt = ptile[w];

  short8 qf[2][2];
  #pragma unroll
  for (int rt=0;rt<2;rt++){
    qf[rt][0] = *(const short8*)(qp + (rt*16+lr)*DKK + lg*8);
    qf[rt][1] = *(const short8*)(qp + (rt*16+lr)*DKK + 32 + lg*8);
  }

  f32x4 acc[2][4];
  #pragma unroll
  for (int rt=0;rt<2;rt++)
    #pragma unroll
    for (int dt=0;dt<4;dt++){ f32x4 z={0.f,0.f,0.f,0.f}; acc[rt][dt]=z; }
  float rsum[2] = {0.f, 0.f};

  short8 kc[4];
  #pragma unroll
  for (int s=0;s<4;s++)
    kc[s] = *(const short8*)(kp + ((size_t)par*4 + s)*512 + lane*8);

  for (int i=0;i<32;i++){
    int c = par + 2*i;
    short8 vc0 = *(const short8*)(vp + ((size_t)c*4 + 0)*512 + lane*8);
    short8 vc1 = *(const short8*)(vp + ((size_t)c*4 + 1)*512 + lane*8);
    short8 ka0=kc[0], ka1=kc[1], kb0=kc[2], kb1=kc[3];
    if (i < 31){
      #pragma unroll
      for (int s=0;s<4;s++)
        kc[s] = *(const short8*)(kp + ((size_t)(c+2)*4 + s)*512 + lane*8);
    }
    #pragma unroll
    for (int rt=0;rt<2;rt++){
      f32x4 sA = {0.f,0.f,0.f,0.f}, sB = {0.f,0.f,0.f,0.f};
      sA = __builtin_amdgcn_mfma_f32_16x16x32_bf16(ka0, qf[rt][0], sA, 0,0,0);
      sA = __builtin_amdgcn_mfma_f32_16x16x32_bf16(ka1, qf[rt][1], sA, 0,0,0);
      sB = __builtin_amdgcn_mfma_f32_16x16x32_bf16(kb0, qf[rt][0], sB, 0,0,0);
      sB = __builtin_amdgcn_mfma_f32_16x16x32_bf16(kb1, qf[rt][1], sB, 0,0,0);
      u16x4 hA, hB;
      #pragma unroll
      for (int r=0;r<4;r++){
        float pA = __builtin_exp2f(sA[r]);
        float pB = __builtin_exp2f(sB[r]);
        rsum[rt] += pA + pB;
        hA[r] = f2bf(pA);
        hB[r] = f2bf(pB);
      }
      *(u16x4*)(myt + (rt*16+lr)*40 + lg*4)      = hA;
      *(u16x4*)(myt + (rt*16+lr)*40 + 16 + lg*4) = hB;
    }
    short8 vc2 = *(const short8*)(vp + ((size_t)c*4 + 2)*512 + lane*8);
    short8 vc3 = *(const short8*)(vp + ((size_t)c*4 + 3)*512 + lane*8);
    #pragma unroll
    for (int rt=0;rt<2;rt++){
      short8 pa = *(const short8*)(myt + (rt*16+lr)*40 + lg*8);
      acc[rt][0] = __builtin_amdgcn_mfma_f32_16x16x32_bf16(pa, vc0, acc[rt][0], 0,0,0);
      acc[rt][1] = __builtin_amdgcn_mfma_f32_16x16x32_bf16(pa, vc1, acc[rt][1], 0,0,0);
      acc[rt][2] = __builtin_amdgcn_mfma_f32_16x16x32_bf16(pa, vc2, acc[rt][2], 0,0,0);
      acc[rt][3] = __builtin_amdgcn_mfma_f32_16x16x32_bf16(pa, vc3, acc[rt][3], 0,0,0);
    }
  }

  #pragma unroll
  for (int rt=0;rt<2;rt++){
    float v = rsum[rt];
    v += __shfl_xor(v, 16);
    v += __shfl_xor(v, 32);
    if (lg == 0) rsbuf[w][rt*16 + lr] = v;
  }
  if (par == 1){
    #pragma unroll
    for (int rt=0;rt<2;rt++)
      #pragma unroll
      for (int dt=0;dt<4;dt++)
        accbuf[lane][rt*4+dt] = acc[rt][dt];
  }
  __syncthreads();

  float il[2];
  #pragma unroll
  for (int rt=0;rt<2;rt++)
    il[rt] = 1.0f / (rsbuf[0][rt*16 + lr] + rsbuf[1][rt*16 + lr]);

  if (par == 0){
    int b_ = bh >> 4, h_ = bh & 15;
    #pragma unroll
    for (int rt=0;rt<2;rt++){
      #pragma unroll
      for (int dt=0;dt<4;dt++)
        acc[rt][dt] += accbuf[lane][rt*4+dt];
      #pragma unroll
      for (int r=0;r<4;r++){
        float ilr = __shfl(il[rt], lg*4 + r, 16);
        int row = qg*32 + rt*16 + lg*4 + r;
        #pragma unroll
        for (int dt=0;dt<4;dt++){
          float vv = acc[rt][dt][r] * ilr;
          ctx[((size_t)b_*SS + row)*DD + h_*DKK + dt*16 + lr] = f2bf(vv);
        }
      }
    }
  }

  // ---- pass 2: row-half split (rt = par); all 64 chunks; plain stores
  int rt2 = par;
  float myil = il[rt2];
  short8 q0 = qf[rt2][0], q1 = qf[rt2][1];
  #pragma unroll
  for (int s=0;s<4;s++)
    kc[s] = *(const short8*)(kp + (size_t)s*512 + lane*8);
  float* arow = attn_out + ((size_t)bh*SS + qg*32 + rt2*16 + lr)*SS;
  for (int c=0;c<64;c++){
    short8 ka0=kc[0], ka1=kc[1], kb0=kc[2], kb1=kc[3];
    if (c < 63){
      #pragma unroll
      for (int s=0;s<4;s++)
        kc[s] = *(const short8*)(kp + ((size_t)(c+1)*4 + s)*512 + lane*8);
    }
    f32x4 sA = {0.f,0.f,0.f,0.f}, sB = {0.f,0.f,0.f,0.f};
    sA = __builtin_amdgcn_mfma_f32_16x16x32_bf16(ka0, q0, sA, 0,0,0);
    sA = __builtin_amdgcn_mfma_f32_16x16x32_bf16(ka1, q1, sA, 0,0,0);
    sB = __builtin_amdgcn_mfma_f32_16x16x32_bf16(kb0, q0, sB, 0,0,0);
    sB = __builtin_amdgcn_mfma_f32_16x16x32_bf16(kb1, q1, sB, 0,0,0);
    f32x4 oA, oB;
    #pragma unroll
    for (int r=0;r<4;r++){
      oA[r] = __builtin_exp2f(sA[r]) * myil;
      oB[r] = __builtin_exp2f(sB[r]) * myil;
    }
    *(f32x4*)(arow + c*32 + lg*4)      = oA;
    *(f32x4*)(arow + c*32 + 16 + lg*4) = oB;
  }
}

// ---------------- launcher ----------------------------------------------------
extern "C" void kernel_launch(void* const* d_in, const int* in_sizes, int n_in,
                              void* d_out, int out_size, void* d_ws, size_t ws_size,
                              hipStream_t stream)
{
  const float* Q   = (const float*)d_in[0];
  const float* Kin = (const float*)d_in[1];
  const float* V   = (const float*)d_in[2];
  const float* Wq  = (const float*)d_in[3];
  const float* bq  = (const float*)d_in[4];
  const float* Wk  = (const float*)d_in[5];
  const float* bk  = (const float*)d_in[6];
  const float* Wv  = (const float*)d_in[7];
  const float* bv  = (const float*)d_in[8];
  const float* Wo  = (const float*)d_in[9];
  const float* bo  = (const float*)d_in[10];

  char* ws = (char*)d_ws;
  u16* qh  = (u16*)(ws + (size_t)( 0u<<20));  // [bh][s][64] bf16, pre-scaled
  u16* kfb = (u16*)(ws + (size_t)( 8u<<20));  // K frag-major, 8 MB
  u16* vfb = (u16*)(ws + (size_t)(16u<<20));  // V frag-major, 8 MB
  u16* ctx = (u16*)(ws + (size_t)(24u<<20));  // [4096][1024] bf16

  float* out0     = (float*)d_out;
  float* attn_out = out0 + (size_t)BB*SS*DD;

  ProjArgs pq = { Q,   Wq, bq, qh,   0, QSCALE };
  ProjArgs pk = { Kin, Wk, bk, kfb,  1, 1.0f   };
  ProjArgs pv = { V,   Wv, bv, vfb,  2, 1.0f   };
  ProjArgs po = { ctx, Wo, bo, out0, 3, 1.0f   };

  proj_kernel<true><<<dim3(32,8,3), 512, 0, stream>>>(pq, pk, pv);
  attn_fused_kernel<<<dim3(2048), 128, 0, stream>>>(qh, kfb, vfb, attn_out, ctx);
  proj_kernel<false><<<dim3(32,8,1), 512, 0, stream>>>(po, po, po);
}

// Round 11
// 292.987 us; speedup vs baseline: 1.0689x; 1.0689x over previous
//
#include <hip/hip_runtime.h>
#include <stdint.h>

// Problem constants
#define BB 2
#define SS 2048
#define DD 1024
#define HH 16
#define DKK 64

typedef unsigned short u16;
typedef short short8 __attribute__((ext_vector_type(8)));
typedef float f32x4 __attribute__((ext_vector_type(4)));
typedef u16 u16x4 __attribute__((ext_vector_type(4)));

// fold (1/sqrt(dk)) * log2(e) into q so scores feed exp2 directly
#define QSCALE 0.18033688011112042f

__device__ __forceinline__ u16 f2bf(float x){
  union { float f; uint32_t u; } v; v.f = x;
  uint32_t r = v.u + 0x7FFFu + ((v.u >> 16) & 1u);
  return (u16)(r >> 16);
}

struct ProjArgs {
  const void* A;      // fp32 [4096][1024] (AF32) or bf16 [4096][1024]
  const float* W;     // fp32 [1024][1024], row n = W[n][:]  (B = W^T)
  const float* bias;  // fp32 [1024]
  void* out;
  int mode;           // 0: q bf16 [bh][s][64]; 1: K frag-major; 2: V frag-major; 3: fp32
  float oscale;       // applied after bias add (QSCALE for q, else 1)
};

// ---------------- projection GEMM, 128x128 tile, 8 waves (2x4), BK=32 --------
template<bool AF32>
__global__ __launch_bounds__(512)
void proj_kernel(ProjArgs a0, ProjArgs a1, ProjArgs a2)
{
  ProjArgs pa = (blockIdx.z == 0) ? a0 : (blockIdx.z == 1 ? a1 : a2);
  const int K = 1024;
  __shared__ __align__(16) u16 As[128*32];
  __shared__ __align__(16) u16 Bs[128*32];

  int tid = threadIdx.x;
  int wid = tid >> 6, lane = tid & 63;
  int lg = lane >> 4, lr = lane & 15;
  int tm = blockIdx.x * 128, tn = blockIdx.y * 128;
  int wr = (wid >> 2) * 64, wc = (wid & 3) * 32;

  const float* Af = (const float*)pa.A;
  const u16*   Ab = (const u16*)pa.A;
  const float* Wf = pa.W;

  f32x4 acc[4][2];
  #pragma unroll
  for (int m=0;m<4;m++)
    #pragma unroll
    for (int n=0;n<2;n++){ f32x4 z = {0.f,0.f,0.f,0.f}; acc[m][n] = z; }

  float4 raf[2], rbf[2];
  short8 rab;

  int s0 = tid,        r0 = s0 >> 3, c0 = (s0 & 7) * 4;
  int s1 = 512 + tid,  r1 = s1 >> 3, c1 = (s1 & 7) * 4;
  int rb_ = tid >> 2,  cb_ = (tid & 3) * 8;

  #define LOAD_TILE(kt)                                                        \
    do {                                                                       \
      if (AF32){                                                               \
        raf[0] = *(const float4*)(Af + (size_t)(tm + r0)*K + (kt) + c0);       \
        raf[1] = *(const float4*)(Af + (size_t)(tm + r1)*K + (kt) + c1);       \
      } else {                                                                 \
        rab = *(const short8*)(Ab + (size_t)(tm + rb_)*K + (kt) + cb_);        \
      }                                                                        \
      rbf[0] = *(const float4*)(Wf + (size_t)(tn + r0)*K + (kt) + c0);         \
      rbf[1] = *(const float4*)(Wf + (size_t)(tn + r1)*K + (kt) + c1);         \
    } while (0)

  LOAD_TILE(0);

  for (int kt = 0; kt < K; kt += 32){
    __syncthreads();
    if (AF32){
      u16x4 h0, h1;
      h0[0]=f2bf(raf[0].x); h0[1]=f2bf(raf[0].y); h0[2]=f2bf(raf[0].z); h0[3]=f2bf(raf[0].w);
      h1[0]=f2bf(raf[1].x); h1[1]=f2bf(raf[1].y); h1[2]=f2bf(raf[1].z); h1[3]=f2bf(raf[1].w);
      *(u16x4*)(As + r0*32 + c0) = h0;
      *(u16x4*)(As + r1*32 + c1) = h1;
    } else {
      *(short8*)(As + rb_*32 + cb_) = rab;
    }
    {
      u16x4 h0, h1;
      h0[0]=f2bf(rbf[0].x); h0[1]=f2bf(rbf[0].y); h0[2]=f2bf(rbf[0].z); h0[3]=f2bf(rbf[0].w);
      h1[0]=f2bf(rbf[1].x); h1[1]=f2bf(rbf[1].y); h1[2]=f2bf(rbf[1].z); h1[3]=f2bf(rbf[1].w);
      *(u16x4*)(Bs + r0*32 + c0) = h0;
      *(u16x4*)(Bs + r1*32 + c1) = h1;
    }
    __syncthreads();
    if (kt + 32 < K) LOAD_TILE(kt + 32);

    short8 af[4], bf[2];
    #pragma unroll
    for (int m=0;m<4;m++) af[m] = *(const short8*)(As + (wr + m*16 + lr)*32 + lg*8);
    #pragma unroll
    for (int n=0;n<2;n++) bf[n] = *(const short8*)(Bs + (wc + n*16 + lr)*32 + lg*8);
    #pragma unroll
    for (int m=0;m<4;m++)
      #pragma unroll
      for (int n=0;n<2;n++)
        acc[m][n] = __builtin_amdgcn_mfma_f32_16x16x32_bf16(af[m], bf[n], acc[m][n], 0,0,0);
  }
  #undef LOAD_TILE

  #pragma unroll
  for (int m=0;m<4;m++){
    #pragma unroll
    for (int n=0;n<2;n++){
      #pragma unroll
      for (int r=0;r<4;r++){
        int gm = tm + wr + m*16 + lg*4 + r;
        int gn = tn + wc + n*16 + lr;
        float v = (acc[m][n][r] + pa.bias[gn]) * pa.oscale;
        if (pa.mode == 3){
          ((float*)pa.out)[(size_t)gm*DD + gn] = v;
        } else {
          int b_ = gm >> 11, s_ = gm & 2047;
          int h_ = gn >> 6,  d_ = gn & 63;
          int bh = b_*HH + h_;
          u16 hv = f2bf(v);
          if (pa.mode == 0){
            ((u16*)pa.out)[((size_t)bh*SS + s_)*DKK + d_] = hv;
          } else if (pa.mode == 1){
            // K frag-major
            int c   = s_ >> 5;
            int lr2 = s_ & 15;
            int tl  = (s_ >> 4) & 1;
            int sub = tl*2 + (d_ >> 5);
            int lg2 = (d_ >> 3) & 3;
            int e   = d_ & 7;
            ((u16*)pa.out)[(((size_t)bh*64 + c)*4 + sub)*512 + (lg2*16 + lr2)*8 + e] = hv;
          } else {
            // V frag-major
            int c   = s_ >> 5;
            int lg2 = (s_ >> 3) & 3;
            int e   = s_ & 7;
            int dt  = d_ >> 4;
            int lr2 = d_ & 15;
            ((u16*)pa.out)[(((size_t)bh*64 + c)*4 + dt)*512 + (lg2*16 + lr2)*8 + e] = hv;
          }
        }
      }
    }
  }
}

// ---------------- fused attention (round-9 base; pass-2 parity chunk-split) --
// Block = 256 thr = 4 waves = 2 wave-pairs. Pair p owns 32 q-rows (qg).
// Pass 1: waves split K-chunks by parity: swapped QK^T -> exp2 -> partial
//   rowsum + partial PV. One barrier, combine partials via LDS; even wave
//   stores ctx.
// Pass 2 (changed this round): waves split K-chunks by parity, each wave
//   computes ALL 32 rows for its 32 chunks -> per-wave K reads halved
//   (128 KB vs 256 KB); same MFMA/exp2/store counts. Pass-2 L2 K traffic
//   drops 1 GB -> 512 MB. XCD swizzle: each XCD owns 4 bh slices (<= L2).
__global__ __launch_bounds__(256, 3)
void attn_fused_kernel(const u16* __restrict__ qb, const u16* __restrict__ kf,
                       const u16* __restrict__ vf, float* __restrict__ attn_out,
                       u16* __restrict__ ctx)
{
  __shared__ __align__(16) u16 ptile[4][1280];    // per-wave [32][40] u16
  __shared__ f32x4 accbuf[2][64][8];              // 16 KB pair-combine
  __shared__ float rsbuf[4][32];

  int tid = threadIdx.x;
  int w = tid >> 6, lane = tid & 63;
  int lg = lane >> 4, lr = lane & 15;
  int p = w >> 1, par = w & 1;
  int L  = blockIdx.x;                  // 0..1023
  int bh = (L & 7)*4 + ((L >> 3) & 3);  // XCD (L%8) owns bh in [4x, 4x+3]
  int qg = ((L >> 5) << 1) + p;         // 0..63, 32 q-rows

  const u16* qp = qb + ((size_t)bh*SS + qg*32)*DKK;
  const u16* kp = kf + (size_t)bh*131072;
  const u16* vp = vf + (size_t)bh*131072;
  u16* myt = ptile[w];

  short8 qf[2][2];
  #pragma unroll
  for (int rt=0;rt<2;rt++){
    qf[rt][0] = *(const short8*)(qp + (rt*16+lr)*DKK + lg*8);
    qf[rt][1] = *(const short8*)(qp + (rt*16+lr)*DKK + 32 + lg*8);
  }

  f32x4 acc[2][4];
  #pragma unroll
  for (int rt=0;rt<2;rt++)
    #pragma unroll
    for (int dt=0;dt<4;dt++){ f32x4 z={0.f,0.f,0.f,0.f}; acc[rt][dt]=z; }
  float rsum[2] = {0.f, 0.f};

  short8 kc[4];
  #pragma unroll
  for (int s=0;s<4;s++)
    kc[s] = *(const short8*)(kp + ((size_t)par*4 + s)*512 + lane*8);

  for (int i=0;i<32;i++){
    int c = par + 2*i;
    short8 vc0 = *(const short8*)(vp + ((size_t)c*4 + 0)*512 + lane*8);
    short8 vc1 = *(const short8*)(vp + ((size_t)c*4 + 1)*512 + lane*8);
    short8 ka0=kc[0], ka1=kc[1], kb0=kc[2], kb1=kc[3];
    if (i < 31){
      #pragma unroll
      for (int s=0;s<4;s++)
        kc[s] = *(const short8*)(kp + ((size_t)(c+2)*4 + s)*512 + lane*8);
    }
    #pragma unroll
    for (int rt=0;rt<2;rt++){
      f32x4 sA = {0.f,0.f,0.f,0.f}, sB = {0.f,0.f,0.f,0.f};
      sA = __builtin_amdgcn_mfma_f32_16x16x32_bf16(ka0, qf[rt][0], sA, 0,0,0);
      sA = __builtin_amdgcn_mfma_f32_16x16x32_bf16(ka1, qf[rt][1], sA, 0,0,0);
      sB = __builtin_amdgcn_mfma_f32_16x16x32_bf16(kb0, qf[rt][0], sB, 0,0,0);
      sB = __builtin_amdgcn_mfma_f32_16x16x32_bf16(kb1, qf[rt][1], sB, 0,0,0);
      u16x4 hA, hB;
      #pragma unroll
      for (int r=0;r<4;r++){
        float pA = __builtin_exp2f(sA[r]);
        float pB = __builtin_exp2f(sB[r]);
        rsum[rt] += pA + pB;
        hA[r] = f2bf(pA);
        hB[r] = f2bf(pB);
      }
      *(u16x4*)(myt + (rt*16+lr)*40 + lg*4)      = hA;
      *(u16x4*)(myt + (rt*16+lr)*40 + 16 + lg*4) = hB;
    }
    short8 vc2 = *(const short8*)(vp + ((size_t)c*4 + 2)*512 + lane*8);
    short8 vc3 = *(const short8*)(vp + ((size_t)c*4 + 3)*512 + lane*8);
    #pragma unroll
    for (int rt=0;rt<2;rt++){
      short8 pa = *(const short8*)(myt + (rt*16+lr)*40 + lg*8);
      acc[rt][0] = __builtin_amdgcn_mfma_f32_16x16x32_bf16(pa, vc0, acc[rt][0], 0,0,0);
      acc[rt][1] = __builtin_amdgcn_mfma_f32_16x16x32_bf16(pa, vc1, acc[rt][1], 0,0,0);
      acc[rt][2] = __builtin_amdgcn_mfma_f32_16x16x32_bf16(pa, vc2, acc[rt][2], 0,0,0);
      acc[rt][3] = __builtin_amdgcn_mfma_f32_16x16x32_bf16(pa, vc3, acc[rt][3], 0,0,0);
    }
  }

  #pragma unroll
  for (int rt=0;rt<2;rt++){
    float v = rsum[rt];
    v += __shfl_xor(v, 16);
    v += __shfl_xor(v, 32);
    if (lg == 0) rsbuf[w][rt*16 + lr] = v;
  }
  if (par == 1){
    #pragma unroll
    for (int rt=0;rt<2;rt++)
      #pragma unroll
      for (int dt=0;dt<4;dt++)
        accbuf[p][lane][rt*4+dt] = acc[rt][dt];
  }
  __syncthreads();

  float il[2];
  #pragma unroll
  for (int rt=0;rt<2;rt++)
    il[rt] = 1.0f / (rsbuf[p*2][rt*16 + lr] + rsbuf[p*2+1][rt*16 + lr]);

  if (par == 0){
    int b_ = bh >> 4, h_ = bh & 15;
    #pragma unroll
    for (int rt=0;rt<2;rt++){
      #pragma unroll
      for (int dt=0;dt<4;dt++)
        acc[rt][dt] += accbuf[p][lane][rt*4+dt];
      #pragma unroll
      for (int r=0;r<4;r++){
        float ilr = __shfl(il[rt], lg*4 + r, 16);
        int row = qg*32 + rt*16 + lg*4 + r;
        #pragma unroll
        for (int dt=0;dt<4;dt++){
          float vv = acc[rt][dt][r] * ilr;
          ctx[((size_t)b_*SS + row)*DD + h_*DKK + dt*16 + lr] = f2bf(vv);
        }
      }
    }
  }

  // ---- pass 2: parity chunk-split; each wave ALL 32 rows, 32 chunks ----
  #pragma unroll
  for (int s=0;s<4;s++)
    kc[s] = *(const short8*)(kp + ((size_t)par*4 + s)*512 + lane*8);
  float* arow0 = attn_out + ((size_t)bh*SS + qg*32 + lr)*SS;        // rt=0 rows
  float* arow1 = attn_out + ((size_t)bh*SS + qg*32 + 16 + lr)*SS;   // rt=1 rows
  for (int i=0;i<32;i++){
    int c = par + 2*i;
    short8 ka0=kc[0], ka1=kc[1], kb0=kc[2], kb1=kc[3];
    if (i < 31){
      #pragma unroll
      for (int s=0;s<4;s++)
        kc[s] = *(const short8*)(kp + ((size_t)(c+2)*4 + s)*512 + lane*8);
    }
    #pragma unroll
    for (int rt=0;rt<2;rt++){
      f32x4 sA = {0.f,0.f,0.f,0.f}, sB = {0.f,0.f,0.f,0.f};
      sA = __builtin_amdgcn_mfma_f32_16x16x32_bf16(ka0, qf[rt][0], sA, 0,0,0);
      sA = __builtin_amdgcn_mfma_f32_16x16x32_bf16(ka1, qf[rt][1], sA, 0,0,0);
      sB = __builtin_amdgcn_mfma_f32_16x16x32_bf16(kb0, qf[rt][0], sB, 0,0,0);
      sB = __builtin_amdgcn_mfma_f32_16x16x32_bf16(kb1, qf[rt][1], sB, 0,0,0);
      float myil = il[rt];
      f32x4 oA, oB;
      #pragma unroll
      for (int r=0;r<4;r++){
        oA[r] = __builtin_exp2f(sA[r]) * myil;
        oB[r] = __builtin_exp2f(sB[r]) * myil;
      }
      float* arow = (rt == 0) ? arow0 : arow1;
      *(f32x4*)(arow + c*32 + lg*4)      = oA;
      *(f32x4*)(arow + c*32 + 16 + lg*4) = oB;
    }
  }
}

// ---------------- launcher ----------------------------------------------------
extern "C" void kernel_launch(void* const* d_in, const int* in_sizes, int n_in,
                              void* d_out, int out_size, void* d_ws, size_t ws_size,
                              hipStream_t stream)
{
  const float* Q   = (const float*)d_in[0];
  const float* Kin = (const float*)d_in[1];
  const float* V   = (const float*)d_in[2];
  const float* Wq  = (const float*)d_in[3];
  const float* bq  = (const float*)d_in[4];
  const float* Wk  = (const float*)d_in[5];
  const float* bk  = (const float*)d_in[6];
  const float* Wv  = (const float*)d_in[7];
  const float* bv  = (const float*)d_in[8];
  const float* Wo  = (const float*)d_in[9];
  const float* bo  = (const float*)d_in[10];

  char* ws = (char*)d_ws;
  u16* qh  = (u16*)(ws + (size_t)( 0u<<20));  // [bh][s][64] bf16, pre-scaled
  u16* kfb = (u16*)(ws + (size_t)( 8u<<20));  // K frag-major, 8 MB
  u16* vfb = (u16*)(ws + (size_t)(16u<<20));  // V frag-major, 8 MB
  u16* ctx = (u16*)(ws + (size_t)(24u<<20));  // [4096][1024] bf16

  float* out0     = (float*)d_out;
  float* attn_out = out0 + (size_t)BB*SS*DD;

  ProjArgs pq = { Q,   Wq, bq, qh,   0, QSCALE };
  ProjArgs pk = { Kin, Wk, bk, kfb,  1, 1.0f   };
  ProjArgs pv = { V,   Wv, bv, vfb,  2, 1.0f   };
  ProjArgs po = { ctx, Wo, bo, out0, 3, 1.0f   };

  proj_kernel<true><<<dim3(32,8,3), 512, 0, stream>>>(pq, pk, pv);
  attn_fused_kernel<<<dim3(1024), 256, 0, stream>>>(qh, kfb, vfb, attn_out, ctx);
  proj_kernel<false><<<dim3(32,8,1), 512, 0, stream>>>(po, po, po);
}

// Round 12
// 270.426 us; speedup vs baseline: 1.1580x; 1.0834x over previous
//
#include <hip/hip_runtime.h>
#include <stdint.h>

// Problem constants
#define BB 2
#define SS 2048
#define DD 1024
#define HH 16
#define DKK 64

typedef unsigned short u16;
typedef short short8 __attribute__((ext_vector_type(8)));
typedef float f32x4 __attribute__((ext_vector_type(4)));
typedef u16 u16x4 __attribute__((ext_vector_type(4)));

// fold (1/sqrt(dk)) * log2(e) into q so scores feed exp2 directly
#define QSCALE 0.18033688011112042f

__device__ __forceinline__ u16 f2bf(float x){
  union { float f; uint32_t u; } v; v.f = x;
  uint32_t r = v.u + 0x7FFFu + ((v.u >> 16) & 1u);
  return (u16)(r >> 16);
}

typedef __attribute__((address_space(1))) const void gv_t;
typedef __attribute__((address_space(3))) void lv_t;
__device__ __forceinline__ void gload_lds16(const u16* g, u16* l){
  __builtin_amdgcn_global_load_lds((gv_t*)g, (lv_t*)l, 16, 0, 0);
}

// ---------------- fp32 -> bf16 conversion (4 tensors/launch, per-slot n) ----
__global__ __launch_bounds__(256)
void cvt_kernel(const float* __restrict__ a0, const float* __restrict__ a1,
                const float* __restrict__ a2, const float* __restrict__ a3,
                u16* __restrict__ o0, u16* __restrict__ o1,
                u16* __restrict__ o2, u16* __restrict__ o3,
                int n0, int n1, int n2, int n3)
{
  const float* a; u16* o; int n4;
  switch (blockIdx.y) {
    case 0:  a=a0; o=o0; n4=n0; break;
    case 1:  a=a1; o=o1; n4=n1; break;
    case 2:  a=a2; o=o2; n4=n2; break;
    default: a=a3; o=o3; n4=n3; break;
  }
  int stride = gridDim.x * blockDim.x;
  for (int i = blockIdx.x*blockDim.x + threadIdx.x; i < n4; i += stride){
    float4 v = ((const float4*)a)[i];
    u16x4 h;
    h[0]=f2bf(v.x); h[1]=f2bf(v.y); h[2]=f2bf(v.z); h[3]=f2bf(v.w);
    ((u16x4*)o)[i] = h;
  }
}

struct ProjArgs {
  const u16* A;       // bf16 [4096][1024]
  const u16* W;       // bf16 [1024][1024], row n = W[n][:]  (B = W^T)
  const float* bias;  // fp32 [1024]
  void* out;
  int mode;           // 0: q bf16 [bh][s][64]; 1: K frag-major; 2: V frag-major; 3: fp32
  float oscale;       // applied after bias add (QSCALE for q, else 1)
};

// ---------------- projection GEMM (m97 structure) ----------------------------
// 128x128 tile, 4 waves (2x2 of 64x64), BK=32, global_load_lds width-16
// staging into linear LDS, 2-barrier loop, acc[4][4] per wave.
__global__ __launch_bounds__(256)
void proj_kernel(ProjArgs a0, ProjArgs a1, ProjArgs a2)
{
  ProjArgs pa = (blockIdx.z == 0) ? a0 : (blockIdx.z == 1 ? a1 : a2);
  const int K = 1024;
  __shared__ __align__(16) u16 As[128*32];
  __shared__ __align__(16) u16 Bs[128*32];

  int tid = threadIdx.x;
  int wid = tid >> 6, lane = tid & 63;
  int lg = lane >> 4, lr = lane & 15;
  int tm = blockIdx.x * 128, tn = blockIdx.y * 128;
  int wr = (wid >> 1) * 64, wc = (wid & 1) * 64;

  f32x4 acc[4][4];
  #pragma unroll
  for (int m=0;m<4;m++)
    #pragma unroll
    for (int n=0;n<4;n++){ f32x4 z = {0.f,0.f,0.f,0.f}; acc[m][n] = z; }

  // staging map: thread t covers LDS bytes t*16 of the 8 KB tile
  // (row = t>>2 of 128-row half? tile is 128x32: row = t>>2 over 64 rows/issue)
  int sr = tid >> 2;            // 0..63
  int sc = (tid & 3) * 8;       // element col
  const u16* ga0 = pa.A + (size_t)(tm + sr)*K + sc;
  const u16* ga1 = pa.A + (size_t)(tm + 64 + sr)*K + sc;
  const u16* gb0 = pa.W + (size_t)(tn + sr)*K + sc;
  const u16* gb1 = pa.W + (size_t)(tn + 64 + sr)*K + sc;
  u16* la0 = As + sr*32 + sc;
  u16* la1 = As + (64 + sr)*32 + sc;
  u16* lb0 = Bs + sr*32 + sc;
  u16* lb1 = Bs + (64 + sr)*32 + sc;

  for (int kt = 0; kt < K; kt += 32){
    gload_lds16(ga0 + kt, la0);
    gload_lds16(ga1 + kt, la1);
    gload_lds16(gb0 + kt, lb0);
    gload_lds16(gb1 + kt, lb1);
    __syncthreads();            // drains vmcnt -> LDS tiles ready

    short8 af[4], bf[4];
    #pragma unroll
    for (int m=0;m<4;m++) af[m] = *(const short8*)(As + (wr + m*16 + lr)*32 + lg*8);
    #pragma unroll
    for (int n=0;n<4;n++) bf[n] = *(const short8*)(Bs + (wc + n*16 + lr)*32 + lg*8);
    #pragma unroll
    for (int m=0;m<4;m++)
      #pragma unroll
      for (int n=0;n<4;n++)
        acc[m][n] = __builtin_amdgcn_mfma_f32_16x16x32_bf16(af[m], bf[n], acc[m][n], 0,0,0);
    __syncthreads();            // all reads done before next stage overwrites
  }

  // epilogue: C/D layout col = lane&15, row = (lane>>4)*4 + reg
  #pragma unroll
  for (int m=0;m<4;m++){
    #pragma unroll
    for (int n=0;n<4;n++){
      #pragma unroll
      for (int r=0;r<4;r++){
        int gm = tm + wr + m*16 + lg*4 + r;
        int gn = tn + wc + n*16 + lr;
        float v = (acc[m][n][r] + pa.bias[gn]) * pa.oscale;
        if (pa.mode == 3){
          ((float*)pa.out)[(size_t)gm*DD + gn] = v;
        } else {
          int b_ = gm >> 11, s_ = gm & 2047;
          int h_ = gn >> 6,  d_ = gn & 63;
          int bh = b_*HH + h_;
          u16 hv = f2bf(v);
          if (pa.mode == 0){
            ((u16*)pa.out)[((size_t)bh*SS + s_)*DKK + d_] = hv;
          } else if (pa.mode == 1){
            // K frag-major
            int c   = s_ >> 5;
            int lr2 = s_ & 15;
            int tl  = (s_ >> 4) & 1;
            int sub = tl*2 + (d_ >> 5);
            int lg2 = (d_ >> 3) & 3;
            int e   = d_ & 7;
            ((u16*)pa.out)[(((size_t)bh*64 + c)*4 + sub)*512 + (lg2*16 + lr2)*8 + e] = hv;
          } else {
            // V frag-major
            int c   = s_ >> 5;
            int lg2 = (s_ >> 3) & 3;
            int e   = s_ & 7;
            int dt  = d_ >> 4;
            int lr2 = d_ & 15;
            ((u16*)pa.out)[(((size_t)bh*64 + c)*4 + dt)*512 + (lg2*16 + lr2)*8 + e] = hv;
          }
        }
      }
    }
  }
}

// ---------------- fused attention (round-11, unchanged: 293 us baseline) -----
__global__ __launch_bounds__(256, 3)
void attn_fused_kernel(const u16* __restrict__ qb, const u16* __restrict__ kf,
                       const u16* __restrict__ vf, float* __restrict__ attn_out,
                       u16* __restrict__ ctx)
{
  __shared__ __align__(16) u16 ptile[4][1280];    // per-wave [32][40] u16
  __shared__ f32x4 accbuf[2][64][8];              // 16 KB pair-combine
  __shared__ float rsbuf[4][32];

  int tid = threadIdx.x;
  int w = tid >> 6, lane = tid & 63;
  int lg = lane >> 4, lr = lane & 15;
  int p = w >> 1, par = w & 1;
  int L  = blockIdx.x;                  // 0..1023
  int bh = (L & 7)*4 + ((L >> 3) & 3);  // XCD (L%8) owns bh in [4x, 4x+3]
  int qg = ((L >> 5) << 1) + p;         // 0..63, 32 q-rows

  const u16* qp = qb + ((size_t)bh*SS + qg*32)*DKK;
  const u16* kp = kf + (size_t)bh*131072;
  const u16* vp = vf + (size_t)bh*131072;
  u16* myt = ptile[w];

  short8 qf[2][2];
  #pragma unroll
  for (int rt=0;rt<2;rt++){
    qf[rt][0] = *(const short8*)(qp + (rt*16+lr)*DKK + lg*8);
    qf[rt][1] = *(const short8*)(qp + (rt*16+lr)*DKK + 32 + lg*8);
  }

  f32x4 acc[2][4];
  #pragma unroll
  for (int rt=0;rt<2;rt++)
    #pragma unroll
    for (int dt=0;dt<4;dt++){ f32x4 z={0.f,0.f,0.f,0.f}; acc[rt][dt]=z; }
  float rsum[2] = {0.f, 0.f};

  short8 kc[4];
  #pragma unroll
  for (int s=0;s<4;s++)
    kc[s] = *(const short8*)(kp + ((size_t)par*4 + s)*512 + lane*8);

  for (int i=0;i<32;i++){
    int c = par + 2*i;
    short8 vc0 = *(const short8*)(vp + ((size_t)c*4 + 0)*512 + lane*8);
    short8 vc1 = *(const short8*)(vp + ((size_t)c*4 + 1)*512 + lane*8);
    short8 ka0=kc[0], ka1=kc[1], kb0=kc[2], kb1=kc[3];
    if (i < 31){
      #pragma unroll
      for (int s=0;s<4;s++)
        kc[s] = *(const short8*)(kp + ((size_t)(c+2)*4 + s)*512 + lane*8);
    }
    #pragma unroll
    for (int rt=0;rt<2;rt++){
      f32x4 sA = {0.f,0.f,0.f,0.f}, sB = {0.f,0.f,0.f,0.f};
      sA = __builtin_amdgcn_mfma_f32_16x16x32_bf16(ka0, qf[rt][0], sA, 0,0,0);
      sA = __builtin_amdgcn_mfma_f32_16x16x32_bf16(ka1, qf[rt][1], sA, 0,0,0);
      sB = __builtin_amdgcn_mfma_f32_16x16x32_bf16(kb0, qf[rt][0], sB, 0,0,0);
      sB = __builtin_amdgcn_mfma_f32_16x16x32_bf16(kb1, qf[rt][1], sB, 0,0,0);
      u16x4 hA, hB;
      #pragma unroll
      for (int r=0;r<4;r++){
        float pA = __builtin_exp2f(sA[r]);
        float pB = __builtin_exp2f(sB[r]);
        rsum[rt] += pA + pB;
        hA[r] = f2bf(pA);
        hB[r] = f2bf(pB);
      }
      *(u16x4*)(myt + (rt*16+lr)*40 + lg*4)      = hA;
      *(u16x4*)(myt + (rt*16+lr)*40 + 16 + lg*4) = hB;
    }
    short8 vc2 = *(const short8*)(vp + ((size_t)c*4 + 2)*512 + lane*8);
    short8 vc3 = *(const short8*)(vp + ((size_t)c*4 + 3)*512 + lane*8);
    #pragma unroll
    for (int rt=0;rt<2;rt++){
      short8 pa = *(const short8*)(myt + (rt*16+lr)*40 + lg*8);
      acc[rt][0] = __builtin_amdgcn_mfma_f32_16x16x32_bf16(pa, vc0, acc[rt][0], 0,0,0);
      acc[rt][1] = __builtin_amdgcn_mfma_f32_16x16x32_bf16(pa, vc1, acc[rt][1], 0,0,0);
      acc[rt][2] = __builtin_amdgcn_mfma_f32_16x16x32_bf16(pa, vc2, acc[rt][2], 0,0,0);
      acc[rt][3] = __builtin_amdgcn_mfma_f32_16x16x32_bf16(pa, vc3, acc[rt][3], 0,0,0);
    }
  }

  #pragma unroll
  for (int rt=0;rt<2;rt++){
    float v = rsum[rt];
    v += __shfl_xor(v, 16);
    v += __shfl_xor(v, 32);
    if (lg == 0) rsbuf[w][rt*16 + lr] = v;
  }
  if (par == 1){
    #pragma unroll
    for (int rt=0;rt<2;rt++)
      #pragma unroll
      for (int dt=0;dt<4;dt++)
        accbuf[p][lane][rt*4+dt] = acc[rt][dt];
  }
  __syncthreads();

  float il[2];
  #pragma unroll
  for (int rt=0;rt<2;rt++)
    il[rt] = 1.0f / (rsbuf[p*2][rt*16 + lr] + rsbuf[p*2+1][rt*16 + lr]);

  if (par == 0){
    int b_ = bh >> 4, h_ = bh & 15;
    #pragma unroll
    for (int rt=0;rt<2;rt++){
      #pragma unroll
      for (int dt=0;dt<4;dt++)
        acc[rt][dt] += accbuf[p][lane][rt*4+dt];
      #pragma unroll
      for (int r=0;r<4;r++){
        float ilr = __shfl(il[rt], lg*4 + r, 16);
        int row = qg*32 + rt*16 + lg*4 + r;
        #pragma unroll
        for (int dt=0;dt<4;dt++){
          float vv = acc[rt][dt][r] * ilr;
          ctx[((size_t)b_*SS + row)*DD + h_*DKK + dt*16 + lr] = f2bf(vv);
        }
      }
    }
  }

  // ---- pass 2: parity chunk-split; each wave ALL 32 rows, 32 chunks ----
  #pragma unroll
  for (int s=0;s<4;s++)
    kc[s] = *(const short8*)(kp + ((size_t)par*4 + s)*512 + lane*8);
  float* arow0 = attn_out + ((size_t)bh*SS + qg*32 + lr)*SS;        // rt=0 rows
  float* arow1 = attn_out + ((size_t)bh*SS + qg*32 + 16 + lr)*SS;   // rt=1 rows
  for (int i=0;i<32;i++){
    int c = par + 2*i;
    short8 ka0=kc[0], ka1=kc[1], kb0=kc[2], kb1=kc[3];
    if (i < 31){
      #pragma unroll
      for (int s=0;s<4;s++)
        kc[s] = *(const short8*)(kp + ((size_t)(c+2)*4 + s)*512 + lane*8);
    }
    #pragma unroll
    for (int rt=0;rt<2;rt++){
      f32x4 sA = {0.f,0.f,0.f,0.f}, sB = {0.f,0.f,0.f,0.f};
      sA = __builtin_amdgcn_mfma_f32_16x16x32_bf16(ka0, qf[rt][0], sA, 0,0,0);
      sA = __builtin_amdgcn_mfma_f32_16x16x32_bf16(ka1, qf[rt][1], sA, 0,0,0);
      sB = __builtin_amdgcn_mfma_f32_16x16x32_bf16(kb0, qf[rt][0], sB, 0,0,0);
      sB = __builtin_amdgcn_mfma_f32_16x16x32_bf16(kb1, qf[rt][1], sB, 0,0,0);
      float myil = il[rt];
      f32x4 oA, oB;
      #pragma unroll
      for (int r=0;r<4;r++){
        oA[r] = __builtin_exp2f(sA[r]) * myil;
        oB[r] = __builtin_exp2f(sB[r]) * myil;
      }
      float* arow = (rt == 0) ? arow0 : arow1;
      *(f32x4*)(arow + c*32 + lg*4)      = oA;
      *(f32x4*)(arow + c*32 + 16 + lg*4) = oB;
    }
  }
}

// ---------------- launcher ----------------------------------------------------
extern "C" void kernel_launch(void* const* d_in, const int* in_sizes, int n_in,
                              void* d_out, int out_size, void* d_ws, size_t ws_size,
                              hipStream_t stream)
{
  const float* Q   = (const float*)d_in[0];
  const float* Kin = (const float*)d_in[1];
  const float* V   = (const float*)d_in[2];
  const float* Wq  = (const float*)d_in[3];
  const float* bq  = (const float*)d_in[4];
  const float* Wk  = (const float*)d_in[5];
  const float* bk  = (const float*)d_in[6];
  const float* Wv  = (const float*)d_in[7];
  const float* bv  = (const float*)d_in[8];
  const float* Wo  = (const float*)d_in[9];
  const float* bo  = (const float*)d_in[10];

  char* ws = (char*)d_ws;
  u16* QB  = (u16*)(ws + (size_t)( 0u<<20));  // bf16 inputs
  u16* KB  = (u16*)(ws + (size_t)( 8u<<20));
  u16* VB  = (u16*)(ws + (size_t)(16u<<20));
  u16* WQB = (u16*)(ws + (size_t)(24u<<20));
  u16* WKB = (u16*)(ws + (size_t)(26u<<20));
  u16* WVB = (u16*)(ws + (size_t)(28u<<20));
  u16* WOB = (u16*)(ws + (size_t)(30u<<20));
  u16* qh  = (u16*)(ws + (size_t)(32u<<20));  // [bh][s][64] bf16
  u16* kfb = (u16*)(ws + (size_t)(40u<<20));  // K frag-major
  u16* vfb = (u16*)(ws + (size_t)(48u<<20));  // V frag-major
  u16* ctx = (u16*)(ws + (size_t)(56u<<20));  // [4096][1024] bf16

  float* out0     = (float*)d_out;
  float* attn_out = out0 + (size_t)BB*SS*DD;

  int n_qkv = (BB*SS*DD)/4;   // float4 chunks
  int n_w   = (DD*DD)/4;

  cvt_kernel<<<dim3(512,4), 256, 0, stream>>>(Q, Kin, V, Wq, QB, KB, VB, WQB,
                                              n_qkv, n_qkv, n_qkv, n_w);
  cvt_kernel<<<dim3(256,3), 256, 0, stream>>>(Wk, Wv, Wo, Wo, WKB, WVB, WOB, WOB,
                                              n_w, n_w, n_w, 0);

  ProjArgs pq = { QB, WQB, bq, qh,   0, QSCALE };
  ProjArgs pk = { KB, WKB, bk, kfb,  1, 1.0f   };
  ProjArgs pv = { VB, WVB, bv, vfb,  2, 1.0f   };
  ProjArgs po = { ctx, WOB, bo, out0, 3, 1.0f  };

  proj_kernel<<<dim3(32,8,3), 256, 0, stream>>>(pq, pk, pv);
  attn_fused_kernel<<<dim3(1024), 256, 0, stream>>>(qh, kfb, vfb, attn_out, ctx);
  proj_kernel<<<dim3(32,8,1), 256, 0, stream>>>(po, po, po);
}